// Round 1
// baseline (642.850 us; speedup 1.0000x reference)
//
#include <hip/hip_runtime.h>

typedef __bf16 bf16_t;
typedef bf16_t bf16x8 __attribute__((ext_vector_type(8)));
typedef float f32x4 __attribute__((ext_vector_type(4)));

#define MFMA16(a, b, c) __builtin_amdgcn_mfma_f32_16x16x32_bf16(a, b, c, 0, 0, 0)

__device__ __forceinline__ unsigned short f2bf(float f) {
    union { float f; unsigned u; } v; v.f = f;
    unsigned r = v.u + 0x7FFFu + ((v.u >> 16) & 1u);  // RNE
    return (unsigned short)(r >> 16);
}
__device__ __forceinline__ float bf2f(unsigned short h) {
    union { unsigned u; float f; } v; v.u = ((unsigned)h) << 16;
    return v.f;
}

// ---------------- cast kernels ----------------
__global__ __launch_bounds__(256) void cast_x_kernel(const float* __restrict__ src,
                                                     unsigned short* __restrict__ dst, int n) {
    int i = (blockIdx.x * 256 + threadIdx.x) * 4;
    if (i >= n) return;
    float4 v = *(const float4*)&src[i];
    union { unsigned short e[4]; uint2 u; } p;
    p.e[0] = f2bf(v.x); p.e[1] = f2bf(v.y); p.e[2] = f2bf(v.z); p.e[3] = f2bf(v.w);
    *(uint2*)&dst[i] = p.u;
}

// src is K x N row-major fp32; dst is N x K row-major bf16 (i.e. B^T)
__global__ __launch_bounds__(256) void castT_kernel(const float* __restrict__ src,
                                                    unsigned short* __restrict__ dst,
                                                    int N, int K) {
    int tid = blockIdx.x * 256 + threadIdx.x;   // exactly N*K/8 threads
    int n  = tid % N;
    int kb = tid / N;
    union { unsigned short e[8]; uint4 v; } u;
#pragma unroll
    for (int j = 0; j < 8; ++j) u.e[j] = f2bf(src[(size_t)(kb * 8 + j) * N + n]);
    *(uint4*)&dst[(size_t)n * K + kb * 8] = u.v;
}

// ---------------- GEMM: C(MxN) = A(MxK,bf16) * Bt(NxK,bf16)^T ----------------
__global__ __launch_bounds__(256) void gemm_bt(
    const unsigned short* __restrict__ A,
    const unsigned short* __restrict__ Bt,
    float* __restrict__ Cf, unsigned short* __restrict__ Cb,
    int M, int N, int K)
{
    __shared__ __align__(16) unsigned short sA[128 * 72];
    __shared__ __align__(16) unsigned short sB[128 * 72];
    int n0 = blockIdx.x * 128, m0 = blockIdx.y * 128;
    int tid = threadIdx.x;
    int lane = tid & 63, w = tid >> 6;
    int wm = (w >> 1) * 64, wn = (w & 1) * 64;
    int lo = lane & 15, quad = lane >> 4;

    f32x4 acc[4][4];
#pragma unroll
    for (int i = 0; i < 4; ++i)
#pragma unroll
        for (int j = 0; j < 4; ++j) acc[i][j] = (f32x4){0.f, 0.f, 0.f, 0.f};

    for (int kt = 0; kt < K; kt += 64) {
#pragma unroll
        for (int c = tid; c < 1024; c += 256) {
            int row = c >> 3, cb = c & 7;
            *(uint4*)&sA[row * 72 + cb * 8] =
                *(const uint4*)&A[(size_t)(m0 + row) * K + kt + cb * 8];
            *(uint4*)&sB[row * 72 + cb * 8] =
                *(const uint4*)&Bt[(size_t)(n0 + row) * K + kt + cb * 8];
        }
        __syncthreads();
#pragma unroll
        for (int ks = 0; ks < 64; ks += 32) {
            bf16x8 af[4], bfr[4];
#pragma unroll
            for (int mi = 0; mi < 4; ++mi)
                af[mi] = *(const bf16x8*)&sA[(wm + mi * 16 + lo) * 72 + ks + quad * 8];
#pragma unroll
            for (int ni = 0; ni < 4; ++ni)
                bfr[ni] = *(const bf16x8*)&sB[(wn + ni * 16 + lo) * 72 + ks + quad * 8];
#pragma unroll
            for (int mi = 0; mi < 4; ++mi)
#pragma unroll
                for (int ni = 0; ni < 4; ++ni)
                    acc[mi][ni] = MFMA16(af[mi], bfr[ni], acc[mi][ni]);
        }
        __syncthreads();
    }

#pragma unroll
    for (int mi = 0; mi < 4; ++mi)
#pragma unroll
        for (int ni = 0; ni < 4; ++ni)
#pragma unroll
            for (int r = 0; r < 4; ++r) {
                int row = m0 + wm + mi * 16 + quad * 4 + r;
                int col = n0 + wn + ni * 16 + lo;
                if (Cf) Cf[(size_t)row * N + col] = acc[mi][ni][r];
                else    Cb[(size_t)row * N + col] = f2bf(acc[mi][ni][r]);
            }
}

// ---------------- RMSNorm + RoPE (+ scatter to outputs) ----------------
// qkv: (B*S, 3072) bf16 rows = [q 2048 | k 512 | v 512]
__global__ __launch_bounds__(256) void rmsrope_kernel(
    const unsigned short* __restrict__ qkv,
    const float* __restrict__ cosb, const float* __restrict__ sinb,
    const float* __restrict__ q_scale, const float* __restrict__ k_scale,
    unsigned short* __restrict__ q_attn, unsigned short* __restrict__ k_attn,
    float* __restrict__ k_out, float* __restrict__ v_out)
{
    int wid = blockIdx.x * 4 + (threadIdx.x >> 6);   // one wave per 64-elem row
    int lane = threadIdx.x & 63;
    int t = wid % 48;          // 0..31 q-head, 32..39 k-group, 40..47 v-group
    int bs = wid / 48;         // 0..4095
    int b = bs >> 11, s = bs & 2047;

    if (t >= 40) {             // v: straight copy to output (b,g,s,d) fp32
        int g = t - 40;
        float val = bf2f(qkv[(size_t)bs * 3072 + 2560 + g * 64 + lane]);
        v_out[(size_t)((b * 8 + g) * 2048 + s) * 64 + lane] = val;
        return;
    }
    bool is_q = (t < 32);
    int col = is_q ? (t * 64) : (2048 + (t - 32) * 64);
    float val = bf2f(qkv[(size_t)bs * 3072 + col + lane]);
    float ss = val * val;
#pragma unroll
    for (int m = 1; m < 64; m <<= 1) ss += __shfl_xor(ss, m);
    float rs = rsqrtf(ss * (1.0f / 64.0f) + 1e-6f);
    float scl = is_q ? q_scale[lane] : k_scale[lane];
    float xn = val * rs * scl;
    float other = __shfl_xor(xn, 32);
    float rot = (lane < 32) ? -other : other;     // [-x2, x1]
    float o = xn * cosb[s * 64 + lane] + rot * sinb[s * 64 + lane];
    if (is_q) {
        // fold 1/sqrt(D)=0.125 into q
        q_attn[(size_t)((b * 32 + t) * 2048 + s) * 64 + lane] = f2bf(o * 0.125f);
    } else {
        int g = t - 32;
        size_t idx = (size_t)((b * 8 + g) * 2048 + s) * 64 + lane;
        k_attn[idx] = f2bf(o);
        k_out[idx] = o;
    }
}

// ---------------- flash attention, causal, GQA ----------------
// block = 4 waves; one 64-row Q tile per block; wave w owns rows w*16..w*16+15
__global__ __launch_bounds__(256) void attn_kernel(
    const unsigned short* __restrict__ q_attn,   // (b,h,s,d) bf16, pre-scaled
    const unsigned short* __restrict__ k_attn,   // (b,g,s,d) bf16 post-rope
    const unsigned short* __restrict__ qkv,      // v read from qkv rows
    unsigned short* __restrict__ ctx)            // (b,s,h*d) bf16
{
    __shared__ __align__(16) unsigned short sK[64 * 72];
    __shared__ __align__(16) unsigned short sVt[64 * 72];   // transposed: [d][kv]
    __shared__ __align__(16) unsigned short sP[4 * 16 * 72];

    int idx = blockIdx.x;
    int qt = 31 - (idx & 31);        // big tiles first
    int bh = idx >> 5;
    int h = bh & 31, b = bh >> 5, g = h >> 2;
    int w = threadIdx.x >> 6, lane = threadIdx.x & 63;
    int lo = lane & 15, quad = lane >> 4;

    const unsigned short* Qbase = q_attn + (size_t)(b * 32 + h) * 2048 * 64;
    const unsigned short* Kbase = k_attn + (size_t)(b * 8 + g) * 2048 * 64;
    const unsigned short* Vbase = qkv + (size_t)b * 2048 * 3072 + 2560 + g * 64;

    int qr = qt * 64 + w * 16 + lo;
    bf16x8 qf0 = *(const bf16x8*)&Qbase[(size_t)qr * 64 + quad * 8];
    bf16x8 qf1 = *(const bf16x8*)&Qbase[(size_t)qr * 64 + 32 + quad * 8];

    f32x4 o_acc[4];
#pragma unroll
    for (int nt = 0; nt < 4; ++nt) o_acc[nt] = (f32x4){0.f, 0.f, 0.f, 0.f};
    float m_old[4] = {-INFINITY, -INFINITY, -INFINITY, -INFINITY};
    float l_run[4] = {0.f, 0.f, 0.f, 0.f};

    for (int kt = 0; kt <= qt; ++kt) {
#pragma unroll
        for (int c = threadIdx.x; c < 512; c += 256) {
            int row = c >> 3, cb = c & 7;
            *(uint4*)&sK[row * 72 + cb * 8] =
                *(const uint4*)&Kbase[(size_t)(kt * 64 + row) * 64 + cb * 8];
            uint4 vv = *(const uint4*)&Vbase[(size_t)(kt * 64 + row) * 3072 + cb * 8];
            union { uint4 v; unsigned short e[8]; } u; u.v = vv;
#pragma unroll
            for (int j = 0; j < 8; ++j) sVt[(cb * 8 + j) * 72 + row] = u.e[j];
        }
        __syncthreads();

        // S = Q K^T  (per wave: 16 x 64)
        f32x4 sc[4];
#pragma unroll
        for (int ct = 0; ct < 4; ++ct) {
            bf16x8 kf0 = *(const bf16x8*)&sK[(ct * 16 + lo) * 72 + quad * 8];
            bf16x8 kf1 = *(const bf16x8*)&sK[(ct * 16 + lo) * 72 + 32 + quad * 8];
            f32x4 z = (f32x4){0.f, 0.f, 0.f, 0.f};
            z = MFMA16(qf0, kf0, z);
            z = MFMA16(qf1, kf1, z);
            sc[ct] = z;
        }

        int row0 = qt * 64 + w * 16 + quad * 4;
        if (kt == qt) {   // only diagonal tile needs the causal mask
#pragma unroll
            for (int ct = 0; ct < 4; ++ct)
#pragma unroll
                for (int r = 0; r < 4; ++r)
                    if (kt * 64 + ct * 16 + lo > row0 + r) sc[ct][r] = -INFINITY;
        }

        float alpha[4];
#pragma unroll
        for (int r = 0; r < 4; ++r) {
            float mx = fmaxf(fmaxf(sc[0][r], sc[1][r]), fmaxf(sc[2][r], sc[3][r]));
#pragma unroll
            for (int m = 1; m < 16; m <<= 1) mx = fmaxf(mx, __shfl_xor(mx, m));
            float mnew = fmaxf(m_old[r], mx);
            alpha[r] = __expf(m_old[r] - mnew);   // first iter: exp(-inf)=0
            m_old[r] = mnew;
        }
#pragma unroll
        for (int ct = 0; ct < 4; ++ct)
#pragma unroll
            for (int r = 0; r < 4; ++r)
                sc[ct][r] = __expf(sc[ct][r] - m_old[r]);
#pragma unroll
        for (int r = 0; r < 4; ++r) {
            float sm = sc[0][r] + sc[1][r] + sc[2][r] + sc[3][r];
#pragma unroll
            for (int m = 1; m < 16; m <<= 1) sm += __shfl_xor(sm, m);
            l_run[r] = l_run[r] * alpha[r] + sm;
        }

        // P: C-layout -> LDS -> A-layout (wave-private region, same-wave DS order)
        unsigned short* Pw = &sP[w * 16 * 72];
#pragma unroll
        for (int ct = 0; ct < 4; ++ct)
#pragma unroll
            for (int r = 0; r < 4; ++r)
                Pw[(quad * 4 + r) * 72 + ct * 16 + lo] = f2bf(sc[ct][r]);

        bf16x8 pf0 = *(const bf16x8*)&Pw[lo * 72 + quad * 8];
        bf16x8 pf1 = *(const bf16x8*)&Pw[lo * 72 + 32 + quad * 8];

#pragma unroll
        for (int nt = 0; nt < 4; ++nt) {
            f32x4 o = o_acc[nt];
#pragma unroll
            for (int r = 0; r < 4; ++r) o[r] *= alpha[r];
            bf16x8 vf0 = *(const bf16x8*)&sVt[(nt * 16 + lo) * 72 + quad * 8];
            bf16x8 vf1 = *(const bf16x8*)&sVt[(nt * 16 + lo) * 72 + 32 + quad * 8];
            o = MFMA16(pf0, vf0, o);
            o = MFMA16(pf1, vf1, o);
            o_acc[nt] = o;
        }
        __syncthreads();
    }

    int srow0 = qt * 64 + w * 16 + quad * 4;
#pragma unroll
    for (int r = 0; r < 4; ++r) {
        float inv = 1.0f / l_run[r];
#pragma unroll
        for (int nt = 0; nt < 4; ++nt) {
            size_t oi = ((size_t)(b * 2048 + srow0 + r)) * 2048 + h * 64 + nt * 16 + lo;
            ctx[oi] = f2bf(o_acc[nt][r] * inv);
        }
    }
}

// ---------------- launch ----------------
extern "C" void kernel_launch(void* const* d_in, const int* in_sizes, int n_in,
                              void* d_out, int out_size, void* d_ws, size_t ws_size,
                              hipStream_t stream)
{
    (void)in_sizes; (void)n_in; (void)out_size; (void)ws_size;
    const float* x       = (const float*)d_in[0];
    // d_in[1] = mask: ignored (causal mask recomputed analytically)
    const float* cosb    = (const float*)d_in[2];
    const float* sinb    = (const float*)d_in[3];
    const float* Wq      = (const float*)d_in[4];
    const float* Wk      = (const float*)d_in[5];
    const float* Wv      = (const float*)d_in[6];
    const float* Wo      = (const float*)d_in[7];
    const float* q_scale = (const float*)d_in[8];
    const float* k_scale = (const float*)d_in[9];

    float* out   = (float*)d_out;                 // (2,2048,2048)
    float* k_out = out + 8388608;                 // (2,8,2048,64)
    float* v_out = k_out + 2097152;               // (2,8,2048,64)

    char* ws = (char*)d_ws;
    size_t off = 0;
    auto alloc = [&](size_t bytes) {
        char* p = ws + off; off += (bytes + 255) & ~(size_t)255; return p;
    };
    unsigned short* x_bf   = (unsigned short*)alloc(4096ull * 2048 * 2);   // 16 MB
    unsigned short* Wqkvt  = (unsigned short*)alloc(3072ull * 2048 * 2);   // 12 MB
    unsigned short* Wot    = (unsigned short*)alloc(2048ull * 2048 * 2);   //  8 MB
    unsigned short* qkv    = (unsigned short*)alloc(4096ull * 3072 * 2);   // 24 MB
    unsigned short* q_attn = (unsigned short*)alloc(4096ull * 2048 * 2);   // 16 MB
    unsigned short* k_attn = (unsigned short*)alloc(2048ull * 2048 * 2);   //  4 MB
    unsigned short* ctx    = (unsigned short*)alloc(4096ull * 2048 * 2);   // 16 MB

    cast_x_kernel<<<8192, 256, 0, stream>>>(x, x_bf, 8388608);
    castT_kernel<<<2048, 256, 0, stream>>>(Wq, Wqkvt, 2048, 2048);
    castT_kernel<<<512, 256, 0, stream>>>(Wk, Wqkvt + 2048ull * 2048, 512, 2048);
    castT_kernel<<<512, 256, 0, stream>>>(Wv, Wqkvt + 2560ull * 2048, 512, 2048);
    castT_kernel<<<2048, 256, 0, stream>>>(Wo, Wot, 2048, 2048);

    // qkv = x @ [Wq|Wk|Wv]  (bf16 out)
    gemm_bt<<<dim3(24, 32), 256, 0, stream>>>(x_bf, Wqkvt, nullptr, qkv, 4096, 3072, 2048);

    rmsrope_kernel<<<49152, 256, 0, stream>>>(qkv, cosb, sinb, q_scale, k_scale,
                                              q_attn, k_attn, k_out, v_out);

    attn_kernel<<<2048, 256, 0, stream>>>(q_attn, k_attn, qkv, ctx);

    // out = ctx @ Wo  (fp32 out)
    gemm_bt<<<dim3(16, 32), 256, 0, stream>>>(ctx, Wot, out, nullptr, 4096, 2048, 2048);
}